// Round 15
// baseline (124.136 us; speedup 1.0000x reference)
//
#include <hip/hip_runtime.h>
#include <hip/hip_bf16.h>

// out[b,o,n] = sum_{k,c} input[b,c,n] * weight[o,k,c] * score[b,k,n]
// B=8, C_IN=16, C_OUT=16, K=4, N=524288. fp32 in/out.
// MFMA: out[b,:,n] = W'(16x64) . Z(64,n), Z[k*16+c,n] = a[k,n]*x[c,n].
//
// r8-r14: schedules, store paths, and TLP (80% occupancy) all converge at
// 116-123us (~3.7 TB/s of 6.3). Surviving theory: DRAM row-activation tax --
// 1KB bursts at 2MB stride = activate per KB. r15: 2KB bursts (W=512) and
// scores staged via gll as well, so ALL reads are 2KB contiguous per visit.
// 20 rows x 2KB x 2buf = 80KB LDS, 512-thr blocks, 2 blocks/CU.

constexpr int B     = 8;
constexpr int C_IN  = 16;
constexpr int C_OUT = 16;
constexpr int KK    = 4;
constexpr long NN   = 524288;            // 2^19
constexpr int W     = 512;               // floats per staged row (2 KB)
constexpr int ROWS  = C_IN + KK;         // 20 staged rows
constexpr int S     = 8;                 // stages per block
constexpr int BPB   = (int)(NN / (W * S));  // 128 blocks per batch
constexpr int GRID  = B * BPB;           // 1024

typedef short bf16x8 __attribute__((ext_vector_type(8)));
typedef float f32x4  __attribute__((ext_vector_type(4)));

__device__ inline short f2bf(float f) {
    return __builtin_bit_cast(short, __float2bfloat16(f));
}

// global->LDS direct copy, 16 B/lane, zero result VGPRs (tracked by vmcnt).
__device__ inline void gll16(const float* gsrc, float* ldst) {
    __builtin_amdgcn_global_load_lds(
        (const __attribute__((address_space(1))) unsigned int*)gsrc,
        (__attribute__((address_space(3))) unsigned int*)ldst,
        16, 0, 0);
}

__global__ __launch_bounds__(512, 4) void
TransformConv1d_39264591020709_kernel(const float* __restrict__ in,
                                      const float* __restrict__ w,
                                      const float* __restrict__ sc,
                                      float* __restrict__ out) {
    __shared__ float lds[2][ROWS][W];    // 80 KB, double-buffered slab (x + scores)

    const int tid  = threadIdx.x;
    const int lane = tid & 63;
    const int wid  = tid >> 6;           // wave 0..7 (owns cols wid*64..+63)
    const int g    = lane >> 4;          // lane group 0..3
    const int col  = lane & 15;

    const int  bi = blockIdx.x;
    const int  b  = bi >> 7;             // / BPB (=128)
    const long n0 = (long)(bi & (BPB - 1)) * (W * S);

    const int ktap = g >> 1;             // score taps {ktap, ktap+2}
    const int c0   = (g & 1) * 8;        // input-channel half

    // A operand (weights): lane holds W'[o=col][kc=g*8+i (+32)] (verified r6-r14).
    bf16x8 w0, w1;
#pragma unroll
    for (int i = 0; i < 8; ++i) {
        w0[i] = f2bf(w[(col * KK + ktap    ) * C_IN + c0 + i]);
        w1[i] = f2bf(w[(col * KK + ktap + 2) * C_IN + c0 + i]);
    }

    const float* inb  = in  + (long)b * C_IN  * NN;
    const float* scb  = sc  + (long)b * KK    * NN;
    float*       outb = out + (long)b * C_OUT * NN;

    // stage: 40 gll16s per block (20 rows x 2 halves), 5 per wave (even).
    // Rows 0..15 = input channels, rows 16..19 = score taps.
    auto STAGE = [&](int s) {
        const long noff = n0 + (long)s * W;
#pragma unroll
        for (int j = 0; j < 5; ++j) {
            const int i    = wid * 5 + j;    // 0..39
            const int row  = i >> 1;
            const int half = i & 1;
            const float* base = (row < C_IN)
                ? inb + (long)row * NN
                : scb + (long)(row - C_IN) * NN;
            gll16(base + noff + half * 256 + lane * 4,
                  &lds[s & 1][row][half * 256]);
        }
    };

    STAGE(0);
    __syncthreads();                     // prologue drain (vmcnt(0)+barrier) — ok once

    for (int s = 0; s < S; ++s) {
        const long nb = n0 + (long)s * W;
        float (*X)[W] = lds[s & 1];

        // ---- prefetch next slab (5 glls/wave, in flight across the whole stage)
        if (s + 1 < S) STAGE(s + 1);
        __builtin_amdgcn_sched_barrier(0);

        // ---- compute 4 tiles from own 64-col slice; scores from LDS rows 16-19;
        // write D back into the consumed x-rows of the same slice ----
#pragma unroll
        for (int u = 0; u < 4; ++u) {
            const int nt = wid * 64 + u * 16;
            float xv[8];
#pragma unroll
            for (int i = 0; i < 8; ++i) xv[i] = X[c0 + i][nt + col];
            const float a0 = X[C_IN + ktap    ][nt + col];
            const float a1 = X[C_IN + ktap + 2][nt + col];
            bf16x8 z0, z1;
#pragma unroll
            for (int i = 0; i < 8; ++i) {
                z0[i] = f2bf(a0 * xv[i]);
                z1[i] = f2bf(a1 * xv[i]);
            }
            f32x4 acc = {0.f, 0.f, 0.f, 0.f};
            acc = __builtin_amdgcn_mfma_f32_16x16x32_bf16(w0, z0, acc, 0, 0, 0);
            acc = __builtin_amdgcn_mfma_f32_16x16x32_bf16(w1, z1, acc, 0, 0, 0);
#pragma unroll
            for (int r = 0; r < 4; ++r)
                X[g * 4 + r][nt + col] = acc[r];   // D[row=g*4+r][col] -> LDS
        }
        __builtin_amdgcn_sched_barrier(0);

        // ---- read back own 16x64 slice (b128), nt store 256B segments ----
#pragma unroll
        for (int q = 0; q < 4; ++q) {
            const int row = q * 4 + (lane >> 4);
            const int cq  = wid * 64 + (lane & 15) * 4;
            f32x4 v = *(const f32x4*)&X[row][cq];          // ds_read_b128
            __builtin_nontemporal_store(v,
                (f32x4*)(outb + (long)row * NN + nb + cq));
        }

        // ---- counted wait: retire glls_{s+1}; only stores_s(4) stay in flight
        if (s + 1 < S) {
            asm volatile("s_waitcnt vmcnt(4)" ::: "memory");
            __builtin_amdgcn_sched_barrier(0);
            __builtin_amdgcn_s_barrier();
            __builtin_amdgcn_sched_barrier(0);
        }
    }
}

extern "C" void kernel_launch(void* const* d_in, const int* in_sizes, int n_in,
                              void* d_out, int out_size, void* d_ws, size_t ws_size,
                              hipStream_t stream) {
    const float* in = (const float*)d_in[0];   // (B, C_IN, N)
    const float* w  = (const float*)d_in[1];   // (C_OUT, K, C_IN)
    const float* sc = (const float*)d_in[2];   // (B, K, N)
    float* out = (float*)d_out;                // (B, C_OUT, N)

    TransformConv1d_39264591020709_kernel<<<GRID, 512, 0, stream>>>(in, w, sc, out);
}

// Round 16
// 114.414 us; speedup vs baseline: 1.0850x; 1.0850x over previous
//
#include <hip/hip_runtime.h>
#include <hip/hip_bf16.h>

// out[b,o,n] = sum_{k,c} input[b,c,n] * weight[o,k,c] * score[b,k,n]
// B=8, C_IN=16, C_OUT=16, K=4, N=524288. fp32 in/out.
// MFMA: out[b,:,n] = W'(16x64) . Z(64,n), Z[k*16+c,n] = a[k,n]*x[c,n].
//
// FINAL (r14 structure, best measured 115.7us): 512-thread blocks, 8 waves,
// 32 KB double-buffered x-slab staged via global_load_lds (register-free MLP),
// scores direct to VGPR, per-stage counted vmcnt + s_barrier, output transposed
// through the consumed x-slab into full-line nt dwordx4 stores.
//
// Exhausted-levers census (r8-r15): schedules (sync-drain / counted depth-2 /
// barrier-free), store paths (nt vs L2), TLP (80% occ), burst size (1->2KB)
// all converge at 116-124us. FETCH fixed at 164MB (L3 ~49% read-hit), WRITE
// fixed at 262MB (exact output) -> traffic is minimal; 426MB @ ~3.7 TB/s is
// the measured memory-system ceiling for this 36-stream strided read/write mix.

constexpr int B     = 8;
constexpr int C_IN  = 16;
constexpr int C_OUT = 16;
constexpr int KK    = 4;
constexpr long NN   = 524288;            // 2^19
constexpr int W     = 256;               // floats per staged row (1 KB)
constexpr int S     = 8;                 // stages per block
constexpr int BPB   = (int)(NN / (W * S));  // 256 blocks per batch
constexpr int GRID  = B * BPB;           // 2048

typedef short bf16x8 __attribute__((ext_vector_type(8)));
typedef float f32x4  __attribute__((ext_vector_type(4)));

__device__ inline short f2bf(float f) {
    return __builtin_bit_cast(short, __float2bfloat16(f));
}

// global->LDS direct copy, 16 B/lane, zero result VGPRs (tracked by vmcnt).
__device__ inline void gll16(const float* gsrc, float* ldst) {
    __builtin_amdgcn_global_load_lds(
        (const __attribute__((address_space(1))) unsigned int*)gsrc,
        (__attribute__((address_space(3))) unsigned int*)ldst,
        16, 0, 0);
}

__global__ __launch_bounds__(512, 8) void
TransformConv1d_39264591020709_kernel(const float* __restrict__ in,
                                      const float* __restrict__ w,
                                      const float* __restrict__ sc,
                                      float* __restrict__ out) {
    __shared__ float lds[2][C_IN][W];    // 32 KB, double-buffered x slab

    const int tid  = threadIdx.x;
    const int lane = tid & 63;
    const int wid  = tid >> 6;           // wave 0..7 (owns cols wid*32..+31)
    const int g    = lane >> 4;          // lane group 0..3
    const int col  = lane & 15;

    const int  bi = blockIdx.x;
    const int  b  = bi >> 8;             // / BPB (=256)
    const long n0 = (long)(bi & (BPB - 1)) * (W * S);

    const int ktap = g >> 1;             // score taps {ktap, ktap+2}
    const int c0   = (g & 1) * 8;        // input-channel half

    // A operand (weights): lane holds W'[o=col][kc=g*8+i (+32)] (verified r6-r14).
    bf16x8 w0, w1;
#pragma unroll
    for (int i = 0; i < 8; ++i) {
        w0[i] = f2bf(w[(col * KK + ktap    ) * C_IN + c0 + i]);
        w1[i] = f2bf(w[(col * KK + ktap + 2) * C_IN + c0 + i]);
    }

    const float* inb  = in  + (long)b * C_IN  * NN;
    const float* scb  = sc  + (long)b * KK    * NN;
    float*       outb = out + (long)b * C_OUT * NN;

    // stage: 2 rows per wave, 1 KB (=1 gll instr) per row.
    auto STAGE = [&](int s) {
        const long noff = n0 + (long)s * W;
#pragma unroll
        for (int j = 0; j < 2; ++j) {
            const int r = wid * 2 + j;
            gll16(inb + (long)r * NN + noff + lane * 4, &lds[s & 1][r][0]);
        }
    };

    STAGE(0);
    __syncthreads();                     // prologue drain (vmcnt(0)+barrier) — ok once

    for (int s = 0; s < S; ++s) {
        const long nb = n0 + (long)s * W;
        float (*X)[W] = lds[s & 1];

        // ---- scores -> VGPR (2 tiles x 2 taps = 4 loads) ----
        float a0[2], a1[2];
#pragma unroll
        for (int u = 0; u < 2; ++u) {
            const int nc = (wid * 2 + u) * 16 + col;
            a0[u] = scb[(long)ktap       * NN + nb + nc];
            a1[u] = scb[(long)(ktap + 2) * NN + nb + nc];
        }
        __builtin_amdgcn_sched_barrier(0);

        // ---- prefetch next slab (2 glls, in flight across the whole stage)
        if (s + 1 < S) STAGE(s + 1);
        __builtin_amdgcn_sched_barrier(0);

        // ---- compute 2 tiles; write output into the consumed x-slab
        // (wave touches ONLY its own 32-col slice for x-reads and out-writes)
#pragma unroll
        for (int u = 0; u < 2; ++u) {
            const int nt = (wid * 2 + u) * 16;
            float xv[8];
#pragma unroll
            for (int i = 0; i < 8; ++i) xv[i] = X[c0 + i][nt + col];
            bf16x8 z0, z1;
#pragma unroll
            for (int i = 0; i < 8; ++i) {
                z0[i] = f2bf(a0[u] * xv[i]);
                z1[i] = f2bf(a1[u] * xv[i]);
            }
            f32x4 acc = {0.f, 0.f, 0.f, 0.f};
            acc = __builtin_amdgcn_mfma_f32_16x16x32_bf16(w0, z0, acc, 0, 0, 0);
            acc = __builtin_amdgcn_mfma_f32_16x16x32_bf16(w1, z1, acc, 0, 0, 0);
#pragma unroll
            for (int r = 0; r < 4; ++r)
                X[g * 4 + r][nt + col] = acc[r];   // D[row=g*4+r][col] -> LDS
        }
        __builtin_amdgcn_sched_barrier(0);

        // ---- read back own 32-col slice (8 rows x 128B per instr), nt store
#pragma unroll
        for (int q = 0; q < 2; ++q) {
            const int row = q * 8 + (lane >> 3);
            const int cq  = wid * 32 + (lane & 7) * 4;
            f32x4 v = *(const f32x4*)&X[row][cq];          // ds_read_b128
            __builtin_nontemporal_store(v,
                (f32x4*)(outb + (long)row * NN + nb + cq));
        }

        // ---- counted wait: retire this stage's glls_{s+1}; newer = stores_s(2)
        if (s + 1 < S) {
            asm volatile("s_waitcnt vmcnt(2)" ::: "memory");
            __builtin_amdgcn_sched_barrier(0);
            __builtin_amdgcn_s_barrier();
            __builtin_amdgcn_sched_barrier(0);
        }
    }
}

extern "C" void kernel_launch(void* const* d_in, const int* in_sizes, int n_in,
                              void* d_out, int out_size, void* d_ws, size_t ws_size,
                              hipStream_t stream) {
    const float* in = (const float*)d_in[0];   // (B, C_IN, N)
    const float* w  = (const float*)d_in[1];   // (C_OUT, K, C_IN)
    const float* sc = (const float*)d_in[2];   // (B, K, N)
    float* out = (float*)d_out;                // (B, C_OUT, N)

    TransformConv1d_39264591020709_kernel<<<GRID, 512, 0, stream>>>(in, w, sc, out);
}